// Round 6
// baseline (325.786 us; speedup 1.0000x reference)
//
#include <hip/hip_runtime.h>
#include <hip/hip_bf16.h>
#include <math.h>
#include <stdint.h>

typedef __bf16 bf16;
typedef __bf16 bf16x8 __attribute__((ext_vector_type(8)));
typedef __bf16 bf16x4v __attribute__((ext_vector_type(4)));
typedef float f32x4 __attribute__((ext_vector_type(4)));

#define NHEADS 4
#define DM 768
#define DB 64
#define HD 192
#define BATCH 8
#define SEQ 1024
#define MROWS 8192

__device__ __forceinline__ void gld_lds16(const void* g, void* l) {
  __builtin_amdgcn_global_load_lds(
      (__attribute__((address_space(1))) void*)(void*)g,
      (__attribute__((address_space(3))) void*)l, 16, 0, 0);
}

// ---------------- converts ----------------
__global__ __launch_bounds__(256) void cvt_f32_bf16(const float* __restrict__ in,
                                                    bf16* __restrict__ out, long n4) {
  long i = (long)blockIdx.x * blockDim.x + threadIdx.x;
  if (i >= n4) return;
  f32x4 v = *(const f32x4*)&in[i * 4];
  bf16x4v t;
  t[0] = (bf16)v[0]; t[1] = (bf16)v[1]; t[2] = (bf16)v[2]; t[3] = (bf16)v[3];
  *(bf16x4v*)&out[i * 4] = t;
}

__global__ __launch_bounds__(256) void transpose_bf16(const float* __restrict__ W,
                                                      bf16* __restrict__ WT, int K, int N) {
  long idx = (long)blockIdx.x * blockDim.x + threadIdx.x;
  if (idx >= (long)K * N) return;
  int k = (int)(idx % K);
  int n = (int)(idx / K);
  WT[(long)n * K + k] = (bf16)W[(long)k * N + n];
}

// V natural [8192][768] bf16 -> VT per batch: out[((b*768)+d)*1024 + s]
__global__ __launch_bounds__(256) void transpose_v(const bf16* __restrict__ Vn,
                                                   bf16* __restrict__ VT) {
  __shared__ bf16 t[64][71];
  const int tid = threadIdx.x;
  const int d0 = blockIdx.x * 64;
  const int s0g = blockIdx.y * 64;
  const int b = s0g >> 10;
  const int sIn = s0g & 1023;
#pragma unroll
  for (int p = 0; p < 2; ++p) {
    int r = p * 32 + (tid >> 3);
    int c = (tid & 7) * 8;
    bf16x8 v = *(const bf16x8*)&Vn[(long)(s0g + r) * DM + d0 + c];
#pragma unroll
    for (int e = 0; e < 8; ++e) t[r][c + e] = v[e];
  }
  __syncthreads();
#pragma unroll
  for (int p = 0; p < 2; ++p) {
    int d = p * 32 + (tid >> 3);
    int s = (tid & 7) * 8;
    bf16x8 v;
#pragma unroll
    for (int e = 0; e < 8; ++e) v[e] = t[s + e][d];
    *(bf16x8*)&VT[((long)(b * DM + d0 + d) << 10) + sIn + s] = v;
  }
}

// ---------------- bias MLP ----------------
__global__ __launch_bounds__(256) void bias_mlp(const float* __restrict__ bloom,
                                                const float* __restrict__ Wb1,
                                                const float* __restrict__ bb1,
                                                const float* __restrict__ Wb2,
                                                const float* __restrict__ bb2,
                                                float* __restrict__ biasarr) {
  int idx = blockIdx.x * blockDim.x + threadIdx.x;
  if (idx >= MROWS) return;
  const float* x = bloom + (long)idx * DB;
  float h[8];
#pragma unroll
  for (int j = 0; j < 8; ++j) h[j] = bb1[j];
  for (int k = 0; k < DB; ++k) {
    float xv = x[k];
#pragma unroll
    for (int j = 0; j < 8; ++j) h[j] = fmaf(xv, Wb1[k * 8 + j], h[j]);
  }
#pragma unroll
  for (int j = 0; j < 8; ++j) {
    float a = h[j];
    h[j] = 0.5f * a * (1.0f + erff(a * 0.7071067811865476f));
  }
  int b = idx >> 10, s = idx & 1023;
#pragma unroll
  for (int o = 0; o < 4; ++o) {
    float a = bb2[o];
#pragma unroll
    for (int j = 0; j < 8; ++j) a = fmaf(h[j], Wb2[j * 4 + o], a);
    biasarr[((long)(b * 4 + o) << 10) + s] = a;
  }
}

// P_lds byte-offset swizzle: 16 rows x 2048B, XOR row into bank bits
__device__ __forceinline__ int pswz(int row, int colb) {
  return row * 2048 + (colb ^ ((row & 7) << 4));
}

// ---------------- fully fused scores+bias+softmax+attn-write+PV ----------------
// 2048 blocks x 256 threads. z = id&31 (b*4+h) -> XCD-affine K/VT reuse.
// Block = 16 q-rows. Wave wk: scores for keys wk*256..+255 (acc[16]=64 f32),
// then PV for d-slice wk*48..+47 over all 1024 keys from swizzled P_lds.
__global__ __launch_bounds__(256) void fused_attn(
    const bf16* __restrict__ Qb, const bf16* __restrict__ Kb,
    const bf16* __restrict__ VT, const float* __restrict__ biasarr,
    float* __restrict__ attn, bf16* __restrict__ ctx) {
  __shared__ __attribute__((aligned(16))) char Pl[16 * 2048];  // 32 KB
  __shared__ float red[128];  // [0:64) max partials, [64:128) sum partials
  const int tid = threadIdx.x;
  const int lane = tid & 63;
  const int wk = tid >> 6;  // 0..3
  const int id = blockIdx.x;
  const int z = id & 31;
  const int m0 = (id >> 5) * 16;
  const int b = z >> 2, h = z & 3;
  const int rsel = lane & 15, ksel = (lane >> 4) * 8;
  const int rl = (lane >> 4) * 4;
  const int kb = wk * 256;

  const bf16* Qbase = Qb + ((long)(b * SEQ + m0)) * DM + h * HD;
  const bf16* Kbase = Kb + ((long)(b * SEQ + kb)) * DM + h * HD;

  f32x4 acc[16] = {};
  for (int k0 = 0; k0 < HD; k0 += 32) {
    bf16x8 af = *(const bf16x8*)(Qbase + (long)rsel * DM + k0 + ksel);
#pragma unroll
    for (int n = 0; n < 16; ++n) {
      bf16x8 bfr = *(const bf16x8*)(Kbase + (long)(n * 16 + rsel) * DM + k0 + ksel);
      acc[n] = __builtin_amdgcn_mfma_f32_16x16x32_bf16(af, bfr, acc[n], 0, 0, 0);
    }
  }

  // scale + bias, wave-local row max (rows rl+j, keys kb+n*16+rsel)
  const float scale = 0.07216878364870323f;
  float bv[16];
#pragma unroll
  for (int n = 0; n < 16; ++n)
    bv[n] = biasarr[(z << 10) + kb + n * 16 + rsel];

  float pm[4];
#pragma unroll
  for (int j = 0; j < 4; ++j) {
    float mx = -1e30f;
#pragma unroll
    for (int n = 0; n < 16; ++n) {
      acc[n][j] = fmaf(acc[n][j], scale, bv[n]);
      mx = fmaxf(mx, acc[n][j]);
    }
    pm[j] = mx;
  }
#pragma unroll
  for (int d = 1; d < 16; d <<= 1)
#pragma unroll
    for (int j = 0; j < 4; ++j) pm[j] = fmaxf(pm[j], __shfl_xor(pm[j], d));
  if (rsel == 0) {
#pragma unroll
    for (int j = 0; j < 4; ++j) red[wk * 16 + rl + j] = pm[j];
  }
  __syncthreads();

  float rmax[4];
#pragma unroll
  for (int j = 0; j < 4; ++j) {
    float mx = red[rl + j];
#pragma unroll
    for (int w = 1; w < 4; ++w) mx = fmaxf(mx, red[w * 16 + rl + j]);
    rmax[j] = mx;
  }

  float ps[4];
#pragma unroll
  for (int j = 0; j < 4; ++j) {
    float s = 0.0f;
#pragma unroll
    for (int n = 0; n < 16; ++n) {
      float e = __expf(acc[n][j] - rmax[j]);
      acc[n][j] = e;
      s += e;
    }
    ps[j] = s;
  }
#pragma unroll
  for (int d = 1; d < 16; d <<= 1)
#pragma unroll
    for (int j = 0; j < 4; ++j) ps[j] += __shfl_xor(ps[j], d);
  if (rsel == 0) {
#pragma unroll
    for (int j = 0; j < 4; ++j) red[64 + wk * 16 + rl + j] = ps[j];
  }
  __syncthreads();

  // normalize -> bf16 -> swizzled LDS
#pragma unroll
  for (int j = 0; j < 4; ++j) {
    float tot = red[64 + rl + j];
#pragma unroll
    for (int w = 1; w < 4; ++w) tot += red[64 + w * 16 + rl + j];
    float inv = 1.0f / tot;
    int row = rl + j;
#pragma unroll
    for (int n = 0; n < 16; ++n)
      *(bf16*)&Pl[pswz(row, (kb + n * 16 + rsel) * 2)] = (bf16)(acc[n][j] * inv);
  }
  __syncthreads();

  // coalesced attn f32 write from P_lds (nontemporal: pure streaming output)
  {
    const int row = tid >> 4;
    const int cw = (tid & 15) * 4;
    const long abase = (((long)z) << 20) + (((long)(m0 + row)) << 10);
#pragma unroll
    for (int i = 0; i < 16; ++i) {
      int col = cw + i * 64;
      bf16x4v pv = *(const bf16x4v*)&Pl[pswz(row, col * 2)];
      f32x4 v;
      v[0] = (float)pv[0]; v[1] = (float)pv[1]; v[2] = (float)pv[2]; v[3] = (float)pv[3];
      __builtin_nontemporal_store(v, (f32x4*)&attn[abase + col]);
    }
  }

  // PV: D[q(16) x d(48)] over K=1024 from P_lds (A) and global VT (B)
  const bf16* Vbase = VT + (((long)(b * DM + h * HD + wk * 48)) << 10);
  f32x4 cacc[3] = {};
#pragma unroll
  for (int kk = 0; kk < 32; ++kk) {
    bf16x8 a = *(const bf16x8*)&Pl[pswz(rsel, kk * 64 + (lane >> 4) * 16)];
#pragma unroll
    for (int nd = 0; nd < 3; ++nd) {
      bf16x8 bb = *(const bf16x8*)(Vbase + (((long)(nd * 16 + rsel)) << 10) + kk * 32 + ksel);
      cacc[nd] = __builtin_amdgcn_mfma_f32_16x16x32_bf16(a, bb, cacc[nd], 0, 0, 0);
    }
  }
#pragma unroll
  for (int nd = 0; nd < 3; ++nd)
#pragma unroll
    for (int j = 0; j < 4; ++j)
      ctx[((long)(b * SEQ + m0 + rl + j)) * DM + h * HD + wk * 48 + nd * 16 + rsel] =
          (bf16)cacc[nd][j];
}

// ---------------- GEMM (A row-major [M,K] bf16, BT row-major [N,K] bf16) ----------------
// MODE 0: bf16 out, ld=DM, +colbias             (Q,K,V projections)
// MODE 4: f32 out = acc + colbias + resid       (final x)
template <int MODE>
__global__ __launch_bounds__(256) void gemm_bt(
    const bf16* __restrict__ A, int lda,
    const bf16* __restrict__ BT, int ldb,
    int M, int N, int Kd,
    const float* __restrict__ colbias,
    const float* __restrict__ resid,
    void* __restrict__ out) {
  __shared__ __attribute__((aligned(16))) bf16 aL[128 * 32];
  __shared__ __attribute__((aligned(16))) bf16 bL[128 * 32];
  const int tid = threadIdx.x;
  const int lane = tid & 63;
  const int wid = tid >> 6;
  const int wr = wid >> 1, wc = wid & 1;
  const int m0 = blockIdx.y * 128, n0 = blockIdx.x * 128;

  f32x4 acc[4][4] = {};

  for (int k0 = 0; k0 < Kd; k0 += 32) {
#pragma unroll
    for (int p = 0; p < 2; ++p) {
      int f = (p * 256 + tid) * 8;
      int row = f >> 5, col = f & 31;
      gld_lds16(A + (long)(m0 + row) * lda + k0 + col, &aL[f]);
    }
#pragma unroll
    for (int p = 0; p < 2; ++p) {
      int f = (p * 256 + tid) * 8;
      int row = f >> 5, col = f & 31;
      int nn = n0 + row;
      nn = nn < N ? nn : N - 1;
      gld_lds16(BT + (long)nn * ldb + k0 + col, &bL[f]);
    }
    __syncthreads();

    const int rsel = lane & 15, ksel = (lane >> 4) * 8;
    bf16x8 af[4], bfr[4];
#pragma unroll
    for (int m = 0; m < 4; ++m)
      af[m] = *(const bf16x8*)&aL[(wr * 64 + m * 16 + rsel) * 32 + ksel];
#pragma unroll
    for (int n = 0; n < 4; ++n)
      bfr[n] = *(const bf16x8*)&bL[(wc * 64 + n * 16 + rsel) * 32 + ksel];
#pragma unroll
    for (int m = 0; m < 4; ++m)
#pragma unroll
      for (int n = 0; n < 4; ++n)
        acc[m][n] = __builtin_amdgcn_mfma_f32_16x16x32_bf16(af[m], bfr[n], acc[m][n], 0, 0, 0);
    __syncthreads();
  }

  const int rl = (lane >> 4) * 4, cl = lane & 15;
#pragma unroll
  for (int m = 0; m < 4; ++m) {
#pragma unroll
    for (int n = 0; n < 4; ++n) {
      int ng = n0 + wc * 64 + n * 16 + cl;
      if (ng >= N) continue;
#pragma unroll
      for (int j = 0; j < 4; ++j) {
        int mg = m0 + wr * 64 + m * 16 + rl + j;
        float v = acc[m][n][j];
        if constexpr (MODE == 0) {
          ((bf16*)out)[(long)mg * DM + ng] = (bf16)(v + colbias[ng]);
        } else {
          long o = (long)mg * DM + ng;
          ((float*)out)[o] = v + colbias[ng] + resid[o];
        }
      }
    }
  }
}

// ---------------- layernorm (one wave per row of 768, in place) ----------------
__global__ __launch_bounds__(256) void layernorm_rows(float* x, const float* __restrict__ gam,
                                                      const float* __restrict__ bet) {
  int row = blockIdx.x * 4 + (threadIdx.x >> 6);
  int lane = threadIdx.x & 63;
  float* r = x + (long)row * DM;
  f32x4 v[3];
#pragma unroll
  for (int i = 0; i < 3; ++i) v[i] = *(const f32x4*)&r[i * 256 + lane * 4];
  float s = 0.0f, ss = 0.0f;
#pragma unroll
  for (int i = 0; i < 3; ++i)
#pragma unroll
    for (int j = 0; j < 4; ++j) {
      s += v[i][j];
      ss += v[i][j] * v[i][j];
    }
  for (int d = 1; d < 64; d <<= 1) {
    s += __shfl_xor(s, d);
    ss += __shfl_xor(ss, d);
  }
  float mu = s * (1.0f / 768.0f);
  float var = ss * (1.0f / 768.0f) - mu * mu;
  float rs = 1.0f / sqrtf(var + 1e-5f);
#pragma unroll
  for (int i = 0; i < 3; ++i) {
#pragma unroll
    for (int j = 0; j < 4; ++j) {
      int c = i * 256 + lane * 4 + j;
      v[i][j] = (v[i][j] - mu) * rs * gam[c] + bet[c];
    }
    *(f32x4*)&r[i * 256 + lane * 4] = v[i];
  }
}

// ---------------- launcher ----------------
extern "C" void kernel_launch(void* const* d_in, const int* in_sizes, int n_in,
                              void* d_out, int out_size, void* d_ws, size_t ws_size,
                              hipStream_t stream) {
  const float* Xd = (const float*)d_in[0];
  const float* Xb = (const float*)d_in[1];
  const float* Wq = (const float*)d_in[2];
  const float* bq = (const float*)d_in[3];
  const float* Wk = (const float*)d_in[4];
  const float* bk = (const float*)d_in[5];
  const float* Wv = (const float*)d_in[6];
  const float* bv = (const float*)d_in[7];
  const float* Wb1 = (const float*)d_in[8];
  const float* bb1 = (const float*)d_in[9];
  const float* Wb2 = (const float*)d_in[10];
  const float* bb2 = (const float*)d_in[11];
  const float* Wo = (const float*)d_in[12];
  const float* bo = (const float*)d_in[13];
  const float* lng = (const float*)d_in[14];
  const float* lnb = (const float*)d_in[15];

  float* y = (float*)d_out;                  // 8192*768 f32
  float* attn = y + (long)MROWS * DM;        // 32*1024*1024 f32

  char* w = (char*)d_ws;
  bf16* Xd_bf = (bf16*)w; w += (long)MROWS * DM * 2;   // later reused as ctx
  bf16* Xb_bf = (bf16*)w; w += (long)MROWS * DB * 2;
  bf16* WqT = (bf16*)w; w += (long)DM * DM * 2;
  bf16* WkT = (bf16*)w; w += (long)DM * DB * 2;
  bf16* WvT = (bf16*)w; w += (long)DM * DM * 2;
  bf16* WoT = (bf16*)w; w += (long)DM * DM * 2;
  bf16* Qb = (bf16*)w; w += (long)MROWS * DM * 2;
  bf16* Kb = (bf16*)w; w += (long)MROWS * DM * 2;
  bf16* VTb = (bf16*)w; w += (long)MROWS * DM * 2;
  bf16* Vnb = (bf16*)w; w += (long)MROWS * DM * 2;     // V natural, pre-transpose
  float* biasarr = (float*)w; w += (long)BATCH * NHEADS * SEQ * 4;
  bf16* ctxb = Xd_bf;  // Xd_bf dead after projections; reuse for ctx

  cvt_f32_bf16<<<6144, 256, 0, stream>>>(Xd, Xd_bf, (long)MROWS * DM / 4);
  cvt_f32_bf16<<<512, 256, 0, stream>>>(Xb, Xb_bf, (long)MROWS * DB / 4);
  transpose_bf16<<<2304, 256, 0, stream>>>(Wq, WqT, DM, DM);
  transpose_bf16<<<192, 256, 0, stream>>>(Wk, WkT, DB, DM);
  transpose_bf16<<<2304, 256, 0, stream>>>(Wv, WvT, DM, DM);
  transpose_bf16<<<2304, 256, 0, stream>>>(Wo, WoT, DM, DM);
  bias_mlp<<<32, 256, 0, stream>>>(Xb, Wb1, bb1, Wb2, bb2, biasarr);

  dim3 blk(256);
  // Q = Xd @ Wq + bq
  gemm_bt<0><<<dim3(6, 64, 1), blk, 0, stream>>>(Xd_bf, DM, WqT, DM, MROWS, DM, DM,
                                                 bq, nullptr, Qb);
  // K = Xb @ Wk + bk
  gemm_bt<0><<<dim3(6, 64, 1), blk, 0, stream>>>(Xb_bf, DB, WkT, DB, MROWS, DM, DB,
                                                 bk, nullptr, Kb);
  // V = Xd @ Wv + bv (natural into Vnb), then tiled transpose -> VTb
  gemm_bt<0><<<dim3(6, 64, 1), blk, 0, stream>>>(Xd_bf, DM, WvT, DM, MROWS, DM, DM,
                                                 bv, nullptr, Vnb);
  transpose_v<<<dim3(12, 128), blk, 0, stream>>>(Vnb, VTb);

  // fused: scores + bias + softmax + attn write + PV -> ctx (in Xd_bf region)
  fused_attn<<<2048, blk, 0, stream>>>(Qb, Kb, VTb, biasarr, attn, ctxb);

  // x = ctx @ Wo + bo + resid -> y region, then LN in place
  gemm_bt<4><<<dim3(6, 64, 1), blk, 0, stream>>>(ctxb, DM, WoT, DM, MROWS, DM, DM,
                                                 bo, Xd, y);
  layernorm_rows<<<2048, 256, 0, stream>>>(y, lng, lnb);
}

// Round 7
// 236.257 us; speedup vs baseline: 1.3790x; 1.3790x over previous
//
#include <hip/hip_runtime.h>
#include <hip/hip_bf16.h>
#include <math.h>
#include <stdint.h>

typedef __bf16 bf16;
typedef __bf16 bf16x8 __attribute__((ext_vector_type(8)));
typedef __bf16 bf16x4v __attribute__((ext_vector_type(4)));
typedef float f32x4 __attribute__((ext_vector_type(4)));

#define NHEADS 4
#define DM 768
#define DB 64
#define HD 192
#define BATCH 8
#define SEQ 1024
#define MROWS 8192

__device__ __forceinline__ void gld_lds16(const void* g, void* l) {
  __builtin_amdgcn_global_load_lds(
      (__attribute__((address_space(1))) void*)(void*)g,
      (__attribute__((address_space(3))) void*)l, 16, 0, 0);
}

// ---------------- converts ----------------
__global__ __launch_bounds__(256) void cvt_f32_bf16(const float* __restrict__ in,
                                                    bf16* __restrict__ out, long n4) {
  long i = (long)blockIdx.x * blockDim.x + threadIdx.x;
  if (i >= n4) return;
  f32x4 v = *(const f32x4*)&in[i * 4];
  bf16x4v t;
  t[0] = (bf16)v[0]; t[1] = (bf16)v[1]; t[2] = (bf16)v[2]; t[3] = (bf16)v[3];
  *(bf16x4v*)&out[i * 4] = t;
}

__global__ __launch_bounds__(256) void transpose_bf16(const float* __restrict__ W,
                                                      bf16* __restrict__ WT, int K, int N) {
  long idx = (long)blockIdx.x * blockDim.x + threadIdx.x;
  if (idx >= (long)K * N) return;
  int k = (int)(idx % K);
  int n = (int)(idx / K);
  WT[(long)n * K + k] = (bf16)W[(long)k * N + n];
}

// ---------------- bias MLP ----------------
__global__ __launch_bounds__(256) void bias_mlp(const float* __restrict__ bloom,
                                                const float* __restrict__ Wb1,
                                                const float* __restrict__ bb1,
                                                const float* __restrict__ Wb2,
                                                const float* __restrict__ bb2,
                                                float* __restrict__ biasarr) {
  int idx = blockIdx.x * blockDim.x + threadIdx.x;
  if (idx >= MROWS) return;
  const float* x = bloom + (long)idx * DB;
  float h[8];
#pragma unroll
  for (int j = 0; j < 8; ++j) h[j] = bb1[j];
  for (int k = 0; k < DB; ++k) {
    float xv = x[k];
#pragma unroll
    for (int j = 0; j < 8; ++j) h[j] = fmaf(xv, Wb1[k * 8 + j], h[j]);
  }
#pragma unroll
  for (int j = 0; j < 8; ++j) {
    float a = h[j];
    h[j] = 0.5f * a * (1.0f + erff(a * 0.7071067811865476f));
  }
  int b = idx >> 10, s = idx & 1023;
#pragma unroll
  for (int o = 0; o < 4; ++o) {
    float a = bb2[o];
#pragma unroll
    for (int j = 0; j < 8; ++j) a = fmaf(h[j], Wb2[j * 4 + o], a);
    biasarr[((long)(b * 4 + o) << 10) + s] = a;
  }
}

// ---------------- fused scores + bias + softmax ----------------
// 512 blocks x 512 threads (R2/R4 proven structure). z = id&31 -> XCD-affine K.
// 8 waves each own a 128-col slice of the 1024-key row; LDS-staged coalesced
// epilogue writes attn f32 only.
__global__ __launch_bounds__(512) void scores_softmax(
    const bf16* __restrict__ Qb, const bf16* __restrict__ Kb,
    const float* __restrict__ biasarr, float* __restrict__ attn) {
  __shared__ __attribute__((aligned(16))) bf16 bL[1024 * 32];  // 64 KB
  const int tid = threadIdx.x;
  const int lane = tid & 63;
  const int wid = tid >> 6;
  const int id = blockIdx.x;
  const int z = id & 31;
  const int m0 = (id >> 5) * 64;
  const int b = z >> 2, h = z & 3;
  const bf16* Qbase = Qb + ((long)(b * SEQ + m0)) * DM + h * HD;
  const bf16* Kbase = Kb + ((long)(b * SEQ)) * DM + h * HD;
  const int rsel = lane & 15, ksel = (lane >> 4) * 8;
  const int rl = (lane >> 4) * 4;

  f32x4 acc[4][8] = {};

  for (int k0 = 0; k0 < HD; k0 += 32) {
#pragma unroll
    for (int p = 0; p < 8; ++p) {
      int f = (p * 512 + tid) * 8;
      int row = f >> 5, col = f & 31;
      gld_lds16(Kbase + (long)row * DM + k0 + col, &bL[f]);
    }
    bf16x8 af[4];
#pragma unroll
    for (int m = 0; m < 4; ++m)
      af[m] = *(const bf16x8*)(Qbase + (long)(m * 16 + rsel) * DM + k0 + ksel);
    __syncthreads();
    bf16x8 bfr[8];
#pragma unroll
    for (int n = 0; n < 8; ++n)
      bfr[n] = *(const bf16x8*)&bL[(wid * 128 + n * 16 + rsel) * 32 + ksel];
#pragma unroll
    for (int m = 0; m < 4; ++m)
#pragma unroll
      for (int n = 0; n < 8; ++n)
        acc[m][n] = __builtin_amdgcn_mfma_f32_16x16x32_bf16(af[m], bfr[n], acc[m][n], 0, 0, 0);
    __syncthreads();
  }

  // scale + bias
  float* red = (float*)bL;  // [8][64] partials
  const float scale = 0.07216878364870323f;
  float bv[8];
#pragma unroll
  for (int n = 0; n < 8; ++n)
    bv[n] = biasarr[(z << 10) + wid * 128 + n * 16 + rsel];

  float pm[4][4];
#pragma unroll
  for (int m = 0; m < 4; ++m)
#pragma unroll
    for (int j = 0; j < 4; ++j) {
      float mx = -1e30f;
#pragma unroll
      for (int n = 0; n < 8; ++n) {
        acc[m][n][j] = fmaf(acc[m][n][j], scale, bv[n]);
        mx = fmaxf(mx, acc[m][n][j]);
      }
      pm[m][j] = mx;
    }
#pragma unroll
  for (int d = 1; d < 16; d <<= 1)
#pragma unroll
    for (int m = 0; m < 4; ++m)
#pragma unroll
      for (int j = 0; j < 4; ++j)
        pm[m][j] = fmaxf(pm[m][j], __shfl_xor(pm[m][j], d));
  if (rsel == 0) {
#pragma unroll
    for (int m = 0; m < 4; ++m)
#pragma unroll
      for (int j = 0; j < 4; ++j)
        red[wid * 64 + m * 16 + rl + j] = pm[m][j];
  }
  __syncthreads();
  float rmax[4][4];
#pragma unroll
  for (int m = 0; m < 4; ++m)
#pragma unroll
    for (int j = 0; j < 4; ++j) {
      float mx = -1e30f;
#pragma unroll
      for (int w = 0; w < 8; ++w)
        mx = fmaxf(mx, red[w * 64 + m * 16 + rl + j]);
      rmax[m][j] = mx;
    }
  __syncthreads();

  float ps[4][4];
#pragma unroll
  for (int m = 0; m < 4; ++m)
#pragma unroll
    for (int j = 0; j < 4; ++j) {
      float s = 0.0f;
#pragma unroll
      for (int n = 0; n < 8; ++n) {
        float e = __expf(acc[m][n][j] - rmax[m][j]);
        acc[m][n][j] = e;
        s += e;
      }
      ps[m][j] = s;
    }
#pragma unroll
  for (int d = 1; d < 16; d <<= 1)
#pragma unroll
    for (int m = 0; m < 4; ++m)
#pragma unroll
      for (int j = 0; j < 4; ++j)
        ps[m][j] += __shfl_xor(ps[m][j], d);
  if (rsel == 0) {
#pragma unroll
    for (int m = 0; m < 4; ++m)
#pragma unroll
      for (int j = 0; j < 4; ++j)
        red[wid * 64 + m * 16 + rl + j] = ps[m][j];
  }
  __syncthreads();

  // normalize in place
#pragma unroll
  for (int m = 0; m < 4; ++m)
#pragma unroll
    for (int j = 0; j < 4; ++j) {
      float tot = 0.0f;
#pragma unroll
      for (int w = 0; w < 8; ++w) tot += red[w * 64 + m * 16 + rl + j];
      float inv = 1.0f / tot;
#pragma unroll
      for (int n = 0; n < 8; ++n) acc[m][n][j] *= inv;
    }
  __syncthreads();  // red dead; bL becomes per-wave staging

  // staged coalesced write-out: per wave a private 16x128 f32 region
  float* Lf = (float*)bL + wid * 2048;
  const long arowbase = ((long)z << 20) + ((long)m0 << 10) + wid * 128;
#pragma unroll
  for (int m = 0; m < 4; ++m) {
#pragma unroll
    for (int j = 0; j < 4; ++j)
#pragma unroll
      for (int n = 0; n < 8; ++n)
        Lf[(rl + j) * 128 + n * 16 + rsel] = acc[m][n][j];
    __syncthreads();
#pragma unroll
    for (int it = 0; it < 8; ++it) {
      int row = it * 2 + (lane >> 5);
      int col = (lane & 31) * 4;
      f32x4 v = *(const f32x4*)&Lf[row * 128 + col];
      *(f32x4*)&attn[arowbase + ((long)(m * 16 + row) << 10) + col] = v;
    }
    __syncthreads();
  }
}

// ---------------- GEMM (A row-major [M,K] bf16, BT row-major [N,K] bf16) ----------------
// MODE 0: bf16 out natural +colbias              (K projection)
// MODE 4: f32 out = acc + colbias + resid        (final x)
// MODE 5: A f32 batched (attn), out bf16 ctx at col h*HD (PV)
// MODE 6: fused QV: ng<768 -> Q natural (+cb1); else V scatter-transposed (+cb2)
template <int MODE>
__global__ __launch_bounds__(256) void gemm_bt(
    const bf16* __restrict__ A, int lda,
    const bf16* __restrict__ BT, int ldb,
    const float* __restrict__ Af,
    int M, int N, int Kd,
    const float* __restrict__ cb1,
    const float* __restrict__ cb2,
    const float* __restrict__ resid,
    void* __restrict__ out, void* __restrict__ out2) {
  __shared__ __attribute__((aligned(16))) bf16 aL[128 * 32];
  __shared__ __attribute__((aligned(16))) bf16 bL[128 * 32];
  const int tid = threadIdx.x;
  const int lane = tid & 63;
  const int wid = tid >> 6;
  const int wr = wid >> 1, wc = wid & 1;
  int bx, by, bz;
  if constexpr (MODE == 5) {
    int idd = blockIdx.x;
    bz = idd & 31;
    bx = (idd >> 5) & 1;
    by = idd >> 6;
  } else {
    bx = blockIdx.x; by = blockIdx.y; bz = blockIdx.z;
  }
  const int m0 = by * 128, n0 = bx * 128;
  const int z = bz;

  long boff = 0;
  if (MODE == 5) {
    int b = z >> 2, h = z & 3;
    boff = ((long)(b * DM + h * HD)) << 10;
  }
  const bf16* Bb = BT + boff;
  const float* Afb = (MODE == 5) ? (Af + ((long)z << 20)) : nullptr;

  f32x4 acc[4][4] = {};

  for (int k0 = 0; k0 < Kd; k0 += 32) {
    if constexpr (MODE == 5) {
#pragma unroll
      for (int p = 0; p < 2; ++p) {
        int f = (p * 256 + tid) * 8;
        int row = f >> 5, col = f & 31;
        const float* g = Afb + (long)(m0 + row) * lda + k0 + col;
        f32x4 x0 = *(const f32x4*)g;
        f32x4 x1 = *(const f32x4*)(g + 4);
        bf16x8 t;
        t[0] = (bf16)x0[0]; t[1] = (bf16)x0[1]; t[2] = (bf16)x0[2]; t[3] = (bf16)x0[3];
        t[4] = (bf16)x1[0]; t[5] = (bf16)x1[1]; t[6] = (bf16)x1[2]; t[7] = (bf16)x1[3];
        *(bf16x8*)&aL[f] = t;
      }
    } else {
#pragma unroll
      for (int p = 0; p < 2; ++p) {
        int f = (p * 256 + tid) * 8;
        int row = f >> 5, col = f & 31;
        gld_lds16(A + (long)(m0 + row) * lda + k0 + col, &aL[f]);
      }
    }
#pragma unroll
    for (int p = 0; p < 2; ++p) {
      int f = (p * 256 + tid) * 8;
      int row = f >> 5, col = f & 31;
      int nn = n0 + row;
      nn = nn < N ? nn : N - 1;
      gld_lds16(Bb + (long)nn * ldb + k0 + col, &bL[f]);
    }
    __syncthreads();

    const int rsel = lane & 15, ksel = (lane >> 4) * 8;
    bf16x8 af[4], bfr[4];
#pragma unroll
    for (int m = 0; m < 4; ++m)
      af[m] = *(const bf16x8*)&aL[(wr * 64 + m * 16 + rsel) * 32 + ksel];
#pragma unroll
    for (int n = 0; n < 4; ++n)
      bfr[n] = *(const bf16x8*)&bL[(wc * 64 + n * 16 + rsel) * 32 + ksel];
#pragma unroll
    for (int m = 0; m < 4; ++m)
#pragma unroll
      for (int n = 0; n < 4; ++n)
        acc[m][n] = __builtin_amdgcn_mfma_f32_16x16x32_bf16(af[m], bfr[n], acc[m][n], 0, 0, 0);
    __syncthreads();
  }

  const int rl = (lane >> 4) * 4, cl = lane & 15;
#pragma unroll
  for (int m = 0; m < 4; ++m) {
#pragma unroll
    for (int n = 0; n < 4; ++n) {
      int ng = n0 + wc * 64 + n * 16 + cl;
      if (ng >= N) continue;
#pragma unroll
      for (int j = 0; j < 4; ++j) {
        int mg = m0 + wr * 64 + m * 16 + rl + j;
        float v = acc[m][n][j];
        if constexpr (MODE == 0) {
          ((bf16*)out)[(long)mg * DM + ng] = (bf16)(v + cb1[ng]);
        } else if constexpr (MODE == 5) {
          int b = z >> 2, h = z & 3;
          ((bf16*)out)[(long)(b * SEQ + mg) * DM + h * HD + ng] = (bf16)v;
        } else if constexpr (MODE == 6) {
          if (ng < DM) {
            ((bf16*)out)[(long)mg * DM + ng] = (bf16)(v + cb1[ng]);
          } else {
            int d = ng - DM;
            int b = mg >> 10, s = mg & 1023;
            ((bf16*)out2)[((long)(b * DM + d) << 10) + s] = (bf16)(v + cb2[d]);
          }
        } else {
          long o = (long)mg * DM + ng;
          ((float*)out)[o] = v + cb1[ng] + resid[o];
        }
      }
    }
  }
}

// ---------------- layernorm (one wave per row of 768, in place) ----------------
__global__ __launch_bounds__(256) void layernorm_rows(float* x, const float* __restrict__ gam,
                                                      const float* __restrict__ bet) {
  int row = blockIdx.x * 4 + (threadIdx.x >> 6);
  int lane = threadIdx.x & 63;
  float* r = x + (long)row * DM;
  f32x4 v[3];
#pragma unroll
  for (int i = 0; i < 3; ++i) v[i] = *(const f32x4*)&r[i * 256 + lane * 4];
  float s = 0.0f, ss = 0.0f;
#pragma unroll
  for (int i = 0; i < 3; ++i)
#pragma unroll
    for (int j = 0; j < 4; ++j) {
      s += v[i][j];
      ss += v[i][j] * v[i][j];
    }
  for (int d = 1; d < 64; d <<= 1) {
    s += __shfl_xor(s, d);
    ss += __shfl_xor(ss, d);
  }
  float mu = s * (1.0f / 768.0f);
  float var = ss * (1.0f / 768.0f) - mu * mu;
  float rs = 1.0f / sqrtf(var + 1e-5f);
#pragma unroll
  for (int i = 0; i < 3; ++i) {
#pragma unroll
    for (int j = 0; j < 4; ++j) {
      int c = i * 256 + lane * 4 + j;
      v[i][j] = (v[i][j] - mu) * rs * gam[c] + bet[c];
    }
    *(f32x4*)&r[i * 256 + lane * 4] = v[i];
  }
}

// ---------------- launcher ----------------
extern "C" void kernel_launch(void* const* d_in, const int* in_sizes, int n_in,
                              void* d_out, int out_size, void* d_ws, size_t ws_size,
                              hipStream_t stream) {
  const float* Xd = (const float*)d_in[0];
  const float* Xb = (const float*)d_in[1];
  const float* Wq = (const float*)d_in[2];
  const float* bq = (const float*)d_in[3];
  const float* Wk = (const float*)d_in[4];
  const float* bk = (const float*)d_in[5];
  const float* Wv = (const float*)d_in[6];
  const float* bv = (const float*)d_in[7];
  const float* Wb1 = (const float*)d_in[8];
  const float* bb1 = (const float*)d_in[9];
  const float* Wb2 = (const float*)d_in[10];
  const float* bb2 = (const float*)d_in[11];
  const float* Wo = (const float*)d_in[12];
  const float* bo = (const float*)d_in[13];
  const float* lng = (const float*)d_in[14];
  const float* lnb = (const float*)d_in[15];

  float* y = (float*)d_out;                  // 8192*768 f32
  float* attn = y + (long)MROWS * DM;        // 32*1024*1024 f32

  char* w = (char*)d_ws;
  bf16* Xd_bf = (bf16*)w; w += (long)MROWS * DM * 2;   // later reused as ctx
  bf16* Xb_bf = (bf16*)w; w += (long)MROWS * DB * 2;
  bf16* WqvT = (bf16*)w; w += (long)2 * DM * DM * 2;   // [1536][768]
  bf16* WkT = (bf16*)w; w += (long)DM * DB * 2;
  bf16* WoT = (bf16*)w; w += (long)DM * DM * 2;
  bf16* Qb = (bf16*)w; w += (long)MROWS * DM * 2;
  bf16* Kb = (bf16*)w; w += (long)MROWS * DM * 2;
  bf16* VTb = (bf16*)w; w += (long)MROWS * DM * 2;
  float* biasarr = (float*)w; w += (long)BATCH * NHEADS * SEQ * 4;
  bf16* ctxb = Xd_bf;  // Xd_bf dead after QV projection; reuse for ctx

  cvt_f32_bf16<<<6144, 256, 0, stream>>>(Xd, Xd_bf, (long)MROWS * DM / 4);
  cvt_f32_bf16<<<512, 256, 0, stream>>>(Xb, Xb_bf, (long)MROWS * DB / 4);
  transpose_bf16<<<2304, 256, 0, stream>>>(Wq, WqvT, DM, DM);
  transpose_bf16<<<2304, 256, 0, stream>>>(Wv, WqvT + (long)DM * DM, DM, DM);
  transpose_bf16<<<192, 256, 0, stream>>>(Wk, WkT, DB, DM);
  transpose_bf16<<<2304, 256, 0, stream>>>(Wo, WoT, DM, DM);
  bias_mlp<<<32, 256, 0, stream>>>(Xb, Wb1, bb1, Wb2, bb2, biasarr);

  dim3 blk(256);
  // K = Xb @ Wk + bk
  gemm_bt<0><<<dim3(6, 64, 1), blk, 0, stream>>>(Xb_bf, DB, WkT, DB, nullptr, MROWS, DM, DB,
                                                 bk, nullptr, nullptr, Kb, nullptr);
  // [Q | V] = Xd @ [Wq | Wv]: Q natural -> Qb, V scatter-transposed -> VTb
  gemm_bt<6><<<dim3(12, 64, 1), blk, 0, stream>>>(Xd_bf, DM, WqvT, DM, nullptr, MROWS, 2 * DM, DM,
                                                  bq, bv, nullptr, Qb, VTb);
  // scores + bias + softmax fused -> attn f32 (only)
  scores_softmax<<<512, 512, 0, stream>>>(Qb, Kb, biasarr, attn);
  // ctx = attn @ V  (reads f32 attn, converts during staging)
  gemm_bt<5><<<512, blk, 0, stream>>>(nullptr, SEQ, VTb, SEQ, attn, SEQ, HD, SEQ,
                                      nullptr, nullptr, nullptr, ctxb, nullptr);
  // x = ctx @ Wo + bo + resid -> y region, then LN in place
  gemm_bt<4><<<dim3(6, 64, 1), blk, 0, stream>>>(ctxb, DM, WoT, DM, nullptr, MROWS, DM, DM,
                                                 bo, nullptr, Xd, y, nullptr);
  layernorm_rows<<<2048, 256, 0, stream>>>(y, lng, lnb);
}